// Round 7
// baseline (1165.186 us; speedup 1.0000x reference)
//
#include <hip/hip_runtime.h>
#include <hip/hip_bf16.h>

#define H 192
#define HH (192*192)
#define NLAYER 13

typedef unsigned short u16;
typedef unsigned int u32;

typedef __attribute__((ext_vector_type(8))) short short8;
typedef __attribute__((ext_vector_type(4))) float floatx4;

__device__ __forceinline__ u16 f2bf(float f) {
    u32 u = __float_as_uint(f);
    u32 r = (u + 0x7FFFu + ((u >> 16) & 1u)) >> 16;   // RNE
    return (u16)r;
}
__device__ __forceinline__ float bf2f(u16 h) {
    return __uint_as_float(((u32)h) << 16);
}
__device__ __forceinline__ u32 pack2(float lo, float hi) {
    return (u32)f2bf(lo) | ((u32)f2bf(hi) << 16);
}

// ---------------- CSR construction (scan-free) ----------------

__global__ void hist_kernel(const int* __restrict__ dst, int* __restrict__ counts, int E) {
    int e = blockIdx.x * blockDim.x + threadIdx.x;
    if (e < E) atomicAdd(&counts[dst[e]], 1);
}

__global__ void alloc_kernel(const int* __restrict__ counts, int* __restrict__ rbeg,
                             int* __restrict__ rcnt, int* __restrict__ cursor,
                             int* __restrict__ total, int Nv) {
    int v = blockIdx.x * blockDim.x + threadIdx.x;
    if (v >= Nv) return;
    int c = counts[v];
    int base = atomicAdd(total, c);
    rbeg[v] = base;
    rcnt[v] = c;
    cursor[v] = base;
}

__global__ void scatter_kernel(const int* __restrict__ src, const int* __restrict__ dst,
                               const float* __restrict__ w, int* __restrict__ cursor,
                               int2* __restrict__ ce, int E) {
    int e = blockIdx.x * blockDim.x + threadIdx.x;
    if (e < E) {
        int p = atomicAdd(&cursor[dst[e]], 1);
        int2 pk; pk.x = src[e]; pk.y = __float_as_int(w[e]);
        ce[p] = pk;
    }
}

// ---------------- Weight prep: Wt_hi/Wt_lo[l][n][k] = split(W[l][k][n]) ----------------

__global__ void wprep_kernel(const float* __restrict__ W, u16* __restrict__ Wt_hi,
                             u16* __restrict__ Wt_lo, int total) {
    int idx = blockIdx.x * blockDim.x + threadIdx.x;
    if (idx >= total) return;
    int l = idx / HH;
    int rem = idx - l * HH;
    int k = rem / H;
    int n = rem - k * H;
    float v = W[(size_t)l * HH + (size_t)k * H + n];
    u16 hi = f2bf(v);
    float res = v - bf2f(hi);
    u16 lo = f2bf(res);
    size_t o = (size_t)l * HH + (size_t)n * H + k;
    Wt_hi[o] = hi;
    Wt_lo[o] = lo;
}

// ---------------- features fp32 -> bf16 ----------------

__global__ void conv_kernel(const float* __restrict__ in, u16* __restrict__ out, int total4) {
    int idx = blockIdx.x * blockDim.x + threadIdx.x;
    if (idx >= total4) return;
    float4 v = ((const float4*)in)[idx];
    ushort4 p;
    p.x = f2bf(v.x); p.y = f2bf(v.y); p.z = f2bf(v.z); p.w = f2bf(v.w);
    ((ushort4*)out)[idx] = p;
}

// ---------------- SpMM (pure aggregation): out_bf = adj @ S ----------------

__device__ __forceinline__ void fma8(float acc[8], uint4 q, float w) {
    u32 u[4] = {q.x, q.y, q.z, q.w};
    #pragma unroll
    for (int i = 0; i < 4; i++) {
        float lo = __uint_as_float(u[i] << 16);
        float hi = __uint_as_float(u[i] & 0xFFFF0000u);
        acc[2*i]     += w * lo;
        acc[2*i + 1] += w * hi;
    }
}

__global__ __launch_bounds__(192) void spmm_raw(
    const u16* __restrict__ S, const int* __restrict__ rbeg, const int* __restrict__ rcnt,
    const int2* __restrict__ ce, u16* __restrict__ out, int Nv)
{
    int tid = threadIdx.x;               // 0..191
    int g = tid >> 3;                    // vertex 0..23
    int l = tid & 7;                     // lane within vertex
    int v = blockIdx.x * 24 + g;
    if (v >= Nv) return;
    int beg = rbeg[v], cnt = rcnt[v];
    const int2* cep = ce + beg;
    #pragma unroll
    for (int cg = 0; cg < 3; cg++) {
        int c0 = cg * 64 + l * 8;
        const u16* Sc = S + c0;
        float acc[8] = {};
        int e = 0;
        for (; e + 3 < cnt; e += 4) {
            int2 p0 = cep[e], p1 = cep[e + 1], p2 = cep[e + 2], p3 = cep[e + 3];
            uint4 q0 = *(const uint4*)(Sc + (size_t)p0.x * H);
            uint4 q1 = *(const uint4*)(Sc + (size_t)p1.x * H);
            uint4 q2 = *(const uint4*)(Sc + (size_t)p2.x * H);
            uint4 q3 = *(const uint4*)(Sc + (size_t)p3.x * H);
            fma8(acc, q0, __int_as_float(p0.y));
            fma8(acc, q1, __int_as_float(p1.y));
            fma8(acc, q2, __int_as_float(p2.y));
            fma8(acc, q3, __int_as_float(p3.y));
        }
        for (; e < cnt; e++) {
            int2 p0 = cep[e];
            uint4 q0 = *(const uint4*)(Sc + (size_t)p0.x * H);
            fma8(acc, q0, __int_as_float(p0.y));
        }
        size_t idx = (size_t)v * H + c0;
        ushort4 o0, o1;
        o0.x = f2bf(acc[0]); o0.y = f2bf(acc[1]); o0.z = f2bf(acc[2]); o0.w = f2bf(acc[3]);
        o1.x = f2bf(acc[4]); o1.y = f2bf(acc[5]); o1.z = f2bf(acc[6]); o1.w = f2bf(acc[7]);
        *(ushort4*)&out[idx] = o0;
        *(ushort4*)&out[idx + 4] = o1;
    }
}

// ---------------- MFMA GEMM, LDS-staged weights + coalesced epilogue ----------------
// Block = 4 waves = 64 rows. 3 K-chunks of 64; per chunk the block cooperatively
// stages Wt_hi/Wt_lo[192n][64k] into LDS (stride 72 shorts: 16B-aligned rows,
// 2-way max bank alias = free), then each wave MFMAs its 16 rows x all 192 cols
// from LDS. Epilogue re-partitions via LDS (union'd with B buffer) for fully
// coalesced float4/uint4 global traffic.
// mode 0: out_bf = bf16(relu(C + b))
// mode 1: f = (resid + relu(C + b))*0.5 ; out_f = f ; out_bf = bf16(f)

#define BSTRIDE 72            // shorts per LDS B-row (64 data + 8 pad)

union SharedU {
    struct { u16 h[192 * BSTRIDE]; u16 l[192 * BSTRIDE]; } b;   // 55296 B
    float c[64 * 196];                                          // 50176 B
};

__global__ __launch_bounds__(256, 2) void gemm_fused(
    const u16* __restrict__ A, const u16* __restrict__ Wt_hi, const u16* __restrict__ Wt_lo,
    const float* __restrict__ bias, u16* __restrict__ out_bf, float* __restrict__ out_f,
    const float* __restrict__ resid, int mode, int M)
{
    __shared__ SharedU sh;
    int tid = threadIdx.x;
    int wave = tid >> 6;
    int lane = tid & 63;
    int col = lane & 15;
    int quad = lane >> 4;
    int rm_blk = blockIdx.x * 64;
    int rm = rm_blk + wave * 16;

    // A fragments: lane -> row rm+col, k-window quad*8 + 32*k  (clamped, always valid)
    int arow = rm + col;
    if (arow >= M) arow = M - 1;
    const u16* Ap = A + (size_t)arow * H + quad * 8;
    short8 a[6];
    #pragma unroll
    for (int k = 0; k < 6; k++) a[k] = *(const short8*)(Ap + k * 32);

    floatx4 acc[12];
    #pragma unroll
    for (int nt = 0; nt < 12; nt++) acc[nt] = (floatx4){0.f, 0.f, 0.f, 0.f};

    for (int kc = 0; kc < 3; kc++) {
        __syncthreads();                 // previous chunk's reads done before overwrite
        // stage 192 rows x 64 k of hi and lo: 1536 uint4 each, 6 per thread
        #pragma unroll
        for (int i = 0; i < 6; i++) {
            int idx = tid + i * 256;
            int row = idx >> 3, seg = idx & 7;
            *(uint4*)&sh.b.h[row * BSTRIDE + seg * 8] =
                *(const uint4*)(Wt_hi + (size_t)row * H + kc * 64 + seg * 8);
            *(uint4*)&sh.b.l[row * BSTRIDE + seg * 8] =
                *(const uint4*)(Wt_lo + (size_t)row * H + kc * 64 + seg * 8);
        }
        __syncthreads();
        #pragma unroll
        for (int nt = 0; nt < 12; nt++) {
            int brow = (nt * 16 + col) * BSTRIDE + quad * 8;
            #pragma unroll
            for (int ks = 0; ks < 2; ks++) {
                short8 bh = *(const short8*)&sh.b.h[brow + ks * 32];
                short8 bl = *(const short8*)&sh.b.l[brow + ks * 32];
                acc[nt] = __builtin_amdgcn_mfma_f32_16x16x32_bf16(a[kc*2+ks], bh, acc[nt], 0, 0, 0);
                acc[nt] = __builtin_amdgcn_mfma_f32_16x16x32_bf16(a[kc*2+ks], bl, acc[nt], 0, 0, 0);
            }
        }
    }

    // ---- epilogue: acc -> LDS (C layout: col=lane&15, row=quad*4+r) ----
    __syncthreads();
    int lr = wave * 16 + quad * 4;
    #pragma unroll
    for (int nt = 0; nt < 12; nt++) {
        int n = nt * 16 + col;
        #pragma unroll
        for (int r = 0; r < 4; r++) sh.c[(lr + r) * 196 + n] = acc[nt][r];
    }
    __syncthreads();

    // re-partition: thread -> row tid>>2, 48 contiguous cols
    int r = tid >> 2;
    int c0 = (tid & 3) * 48;
    int grow = rm_blk + r;
    if (grow >= M) return;
    float v[48];
    #pragma unroll
    for (int i = 0; i < 12; i++) {
        float4 q = *(const float4*)&sh.c[r * 196 + c0 + 4 * i];
        float4 b = *(const float4*)&bias[c0 + 4 * i];
        v[4*i+0] = fmaxf(q.x + b.x, 0.f);
        v[4*i+1] = fmaxf(q.y + b.y, 0.f);
        v[4*i+2] = fmaxf(q.z + b.z, 0.f);
        v[4*i+3] = fmaxf(q.w + b.w, 0.f);
    }
    size_t o = (size_t)grow * H + c0;
    if (mode == 1) {
        #pragma unroll
        for (int i = 0; i < 12; i++) {
            float4 f = *(const float4*)&resid[o + 4 * i];
            f.x = (v[4*i+0] + f.x) * 0.5f;
            f.y = (v[4*i+1] + f.y) * 0.5f;
            f.z = (v[4*i+2] + f.z) * 0.5f;
            f.w = (v[4*i+3] + f.w) * 0.5f;
            v[4*i+0] = f.x; v[4*i+1] = f.y; v[4*i+2] = f.z; v[4*i+3] = f.w;
            *(float4*)&out_f[o + 4 * i] = f;
        }
    }
    #pragma unroll
    for (int i = 0; i < 6; i++) {
        uint4 p;
        p.x = pack2(v[8*i+0], v[8*i+1]);
        p.y = pack2(v[8*i+2], v[8*i+3]);
        p.z = pack2(v[8*i+4], v[8*i+5]);
        p.w = pack2(v[8*i+6], v[8*i+7]);
        *(uint4*)&out_bf[o + 8 * i] = p;
    }
}

// ---------------- Output head: coords = (adj@feats) @ W_out + b_out ----------------

__global__ void head_kernel(const u16* __restrict__ A, const float* __restrict__ W,
                            const float* __restrict__ b, float* __restrict__ coords, int M) {
    int row = blockIdx.x * blockDim.x + threadIdx.x;
    if (row >= M) return;
    float a0 = b[0], a1 = b[1], a2 = b[2];
    const u16* Ar = A + (size_t)row * H;
    for (int k = 0; k < H; k++) {
        float x = bf2f(Ar[k]);
        a0 += x * W[k * 3 + 0];
        a1 += x * W[k * 3 + 1];
        a2 += x * W[k * 3 + 2];
    }
    coords[row * 3 + 0] = a0;
    coords[row * 3 + 1] = a1;
    coords[row * 3 + 2] = a2;
}

// ---------------- Launch ----------------

extern "C" void kernel_launch(void* const* d_in, const int* in_sizes, int n_in,
                              void* d_out, int out_size, void* d_ws, size_t ws_size,
                              hipStream_t stream) {
    const float* features = (const float*)d_in[0];
    const int*   edge_src = (const int*)d_in[1];
    const int*   edge_dst = (const int*)d_in[2];
    const float* edge_w   = (const float*)d_in[3];
    const float* Ws       = (const float*)d_in[4];
    const float* bs       = (const float*)d_in[5];
    const float* W_out    = (const float*)d_in[6];
    const float* b_out    = (const float*)d_in[7];

    const int N = in_sizes[0] / H;
    const int E = in_sizes[1];

    float* coords = (float*)d_out;
    float* feats  = coords + (size_t)N * 3;   // fp32 feats output/accumulator

    char* wptr = (char*)d_ws;
    u16* xbuf_bf  = (u16*)wptr;   wptr += (size_t)N * H * sizeof(u16);
    u16* sup      = (u16*)wptr;   wptr += (size_t)N * H * sizeof(u16);
    u16* feats_bf = (u16*)wptr;   wptr += (size_t)N * H * sizeof(u16);
    u16* Wt_hi    = (u16*)wptr;   wptr += (size_t)NLAYER * HH * sizeof(u16);
    u16* Wt_lo    = (u16*)wptr;   wptr += (size_t)NLAYER * HH * sizeof(u16);
    int* counts   = (int*)wptr;   wptr += (size_t)N * sizeof(int);
    int* total    = (int*)wptr;   wptr += 4;                      // contiguous with counts
    int* rbeg     = (int*)wptr;   wptr += (size_t)N * sizeof(int);
    int* rcnt     = (int*)wptr;   wptr += (size_t)N * sizeof(int);
    int* cursor   = (int*)wptr;   wptr += (size_t)N * sizeof(int);
    int2* ce      = (int2*)wptr;  wptr += (size_t)E * sizeof(int2);

    // --- build CSR (dst-indexed, scan-free) ---
    hipMemsetAsync(counts, 0, (size_t)(N + 1) * sizeof(int), stream);  // counts + total
    hist_kernel<<<(E + 255) / 256, 256, 0, stream>>>(edge_dst, counts, E);
    alloc_kernel<<<(N + 255) / 256, 256, 0, stream>>>(counts, rbeg, rcnt, cursor, total, N);
    scatter_kernel<<<(E + 255) / 256, 256, 0, stream>>>(edge_src, edge_dst, edge_w,
                                                        cursor, ce, E);

    // --- weight split/transpose + feature conversion ---
    int wtotal = NLAYER * HH;
    wprep_kernel<<<(wtotal + 255) / 256, 256, 0, stream>>>(Ws, Wt_hi, Wt_lo, wtotal);
    int c4 = N * H / 4;
    conv_kernel<<<(c4 + 255) / 256, 256, 0, stream>>>(features, xbuf_bf, c4);

    int gblocks = (N + 63) / 64;
    int VC = (N + 23) / 24;

    // L0: agg = adj@f ; x0 = relu(agg W0 + b0)
    spmm_raw<<<VC, 192, 0, stream>>>(xbuf_bf, rbeg, rcnt, ce, sup, N);
    gemm_fused<<<gblocks, 256, 0, stream>>>(sup, Wt_hi + 0 * HH, Wt_lo + 0 * HH, bs + 0 * H,
                                            xbuf_bf, nullptr, nullptr, 0, N);
    // L1: agg = adj@x0 ; feats = (features + relu(agg W1 + b1))/2
    spmm_raw<<<VC, 192, 0, stream>>>(xbuf_bf, rbeg, rcnt, ce, sup, N);
    gemm_fused<<<gblocks, 256, 0, stream>>>(sup, Wt_hi + 1 * HH, Wt_lo + 1 * HH, bs + 1 * H,
                                            feats_bf, feats, features, 1, N);

    // blocks 2-6
    for (int i = 2; i < 12; i += 2) {
        spmm_raw<<<VC, 192, 0, stream>>>(feats_bf, rbeg, rcnt, ce, sup, N);
        gemm_fused<<<gblocks, 256, 0, stream>>>(sup, Wt_hi + (size_t)i * HH, Wt_lo + (size_t)i * HH,
                                                bs + (size_t)i * H, xbuf_bf, nullptr, nullptr, 0, N);
        spmm_raw<<<VC, 192, 0, stream>>>(xbuf_bf, rbeg, rcnt, ce, sup, N);
        gemm_fused<<<gblocks, 256, 0, stream>>>(sup, Wt_hi + (size_t)(i+1) * HH, Wt_lo + (size_t)(i+1) * HH,
                                                bs + (size_t)(i+1) * H, feats_bf, feats, feats, 1, N);
    }

    // gc13
    spmm_raw<<<VC, 192, 0, stream>>>(feats_bf, rbeg, rcnt, ce, sup, N);
    gemm_fused<<<gblocks, 256, 0, stream>>>(sup, Wt_hi + 12 * (size_t)HH, Wt_lo + 12 * (size_t)HH,
                                            bs + 12 * H, feats_bf, feats, feats, 1, N);

    // head: coords = (adj@feats) W_out + b_out
    spmm_raw<<<VC, 192, 0, stream>>>(feats_bf, rbeg, rcnt, ce, sup, N);
    head_kernel<<<(N + 255) / 256, 256, 0, stream>>>(sup, W_out, b_out, coords, N);
}

// Round 8
// 934.232 us; speedup vs baseline: 1.2472x; 1.2472x over previous
//
#include <hip/hip_runtime.h>
#include <hip/hip_bf16.h>

#define H 192
#define HH (192*192)
#define NLAYER 13
#define NB_GEMM 170            // blocks per column-third

typedef unsigned short u16;
typedef unsigned int u32;

typedef __attribute__((ext_vector_type(8))) short short8;
typedef __attribute__((ext_vector_type(4))) float floatx4;

__device__ __forceinline__ u16 f2bf(float f) {
    u32 u = __float_as_uint(f);
    u32 r = (u + 0x7FFFu + ((u >> 16) & 1u)) >> 16;   // RNE
    return (u16)r;
}
__device__ __forceinline__ float bf2f(u16 h) {
    return __uint_as_float(((u32)h) << 16);
}

// ---------------- CSR construction (scan-free) ----------------

__global__ void hist_kernel(const int* __restrict__ dst, int* __restrict__ counts, int E) {
    int e = blockIdx.x * blockDim.x + threadIdx.x;
    if (e < E) atomicAdd(&counts[dst[e]], 1);
}

__global__ void alloc_kernel(const int* __restrict__ counts, int* __restrict__ rbeg,
                             int* __restrict__ rcnt, int* __restrict__ cursor,
                             int* __restrict__ total, int Nv) {
    int v = blockIdx.x * blockDim.x + threadIdx.x;
    if (v >= Nv) return;
    int c = counts[v];
    int base = atomicAdd(total, c);
    rbeg[v] = base;
    rcnt[v] = c;
    cursor[v] = base;
}

__global__ void scatter_kernel(const int* __restrict__ src, const int* __restrict__ dst,
                               const float* __restrict__ w, int* __restrict__ cursor,
                               int2* __restrict__ ce, int E) {
    int e = blockIdx.x * blockDim.x + threadIdx.x;
    if (e < E) {
        int p = atomicAdd(&cursor[dst[e]], 1);
        int2 pk; pk.x = src[e]; pk.y = __float_as_int(w[e]);
        ce[p] = pk;
    }
}

// ---------------- Weight prep: Wt_hi/Wt_lo[l][n][k] = split(W[l][k][n]) ----------------

__global__ void wprep_kernel(const float* __restrict__ W, u16* __restrict__ Wt_hi,
                             u16* __restrict__ Wt_lo, int total) {
    int idx = blockIdx.x * blockDim.x + threadIdx.x;
    if (idx >= total) return;
    int l = idx / HH;
    int rem = idx - l * HH;
    int k = rem / H;
    int n = rem - k * H;
    float v = W[(size_t)l * HH + (size_t)k * H + n];
    u16 hi = f2bf(v);
    float res = v - bf2f(hi);
    u16 lo = f2bf(res);
    size_t o = (size_t)l * HH + (size_t)n * H + k;
    Wt_hi[o] = hi;
    Wt_lo[o] = lo;
}

// ---------------- features fp32 -> bf16 ----------------

__global__ void conv_kernel(const float* __restrict__ in, u16* __restrict__ out, int total4) {
    int idx = blockIdx.x * blockDim.x + threadIdx.x;
    if (idx >= total4) return;
    float4 v = ((const float4*)in)[idx];
    ushort4 p;
    p.x = f2bf(v.x); p.y = f2bf(v.y); p.z = f2bf(v.z); p.w = f2bf(v.w);
    ((ushort4*)out)[idx] = p;
}

// ---------------- SpMM (pure aggregation): out_bf = adj @ S ----------------

__device__ __forceinline__ void fma8(float acc[8], uint4 q, float w) {
    u32 u[4] = {q.x, q.y, q.z, q.w};
    #pragma unroll
    for (int i = 0; i < 4; i++) {
        float lo = __uint_as_float(u[i] << 16);
        float hi = __uint_as_float(u[i] & 0xFFFF0000u);
        acc[2*i]     += w * lo;
        acc[2*i + 1] += w * hi;
    }
}

__global__ __launch_bounds__(192) void spmm_raw(
    const u16* __restrict__ S, const int* __restrict__ rbeg, const int* __restrict__ rcnt,
    const int2* __restrict__ ce, u16* __restrict__ out, int Nv)
{
    int tid = threadIdx.x;               // 0..191
    int g = tid >> 3;                    // vertex 0..23
    int l = tid & 7;                     // lane within vertex
    int v = blockIdx.x * 24 + g;
    if (v >= Nv) return;
    int beg = rbeg[v], cnt = rcnt[v];
    const int2* cep = ce + beg;
    #pragma unroll
    for (int cg = 0; cg < 3; cg++) {
        int c0 = cg * 64 + l * 8;
        const u16* Sc = S + c0;
        float acc[8] = {};
        int e = 0;
        for (; e + 3 < cnt; e += 4) {
            int2 p0 = cep[e], p1 = cep[e + 1], p2 = cep[e + 2], p3 = cep[e + 3];
            uint4 q0 = *(const uint4*)(Sc + (size_t)p0.x * H);
            uint4 q1 = *(const uint4*)(Sc + (size_t)p1.x * H);
            uint4 q2 = *(const uint4*)(Sc + (size_t)p2.x * H);
            uint4 q3 = *(const uint4*)(Sc + (size_t)p3.x * H);
            fma8(acc, q0, __int_as_float(p0.y));
            fma8(acc, q1, __int_as_float(p1.y));
            fma8(acc, q2, __int_as_float(p2.y));
            fma8(acc, q3, __int_as_float(p3.y));
        }
        for (; e < cnt; e++) {
            int2 p0 = cep[e];
            uint4 q0 = *(const uint4*)(Sc + (size_t)p0.x * H);
            fma8(acc, q0, __int_as_float(p0.y));
        }
        size_t idx = (size_t)v * H + c0;
        ushort4 o0, o1;
        o0.x = f2bf(acc[0]); o0.y = f2bf(acc[1]); o0.z = f2bf(acc[2]); o0.w = f2bf(acc[3]);
        o1.x = f2bf(acc[4]); o1.y = f2bf(acc[5]); o1.z = f2bf(acc[6]); o1.w = f2bf(acc[7]);
        *(ushort4*)&out[idx] = o0;
        *(ushort4*)&out[idx + 4] = o1;
    }
}

// ---------------- MFMA GEMM, weights-stationary in LDS (fragment-ordered) ----------------
// grid = (NB_GEMM, 3). Block stages its 64-col third of Wt_hi/Wt_lo ONCE in
// MFMA-fragment order (lane-contiguous 16B => conflict-free ds_read_b128),
// then 4 waves sweep 32-row units of A, B-frags reused across both 16-row
// chunks. Epilogue: 16 consecutive u16 per quarter-wave (32B chunks).
// mode 0: out_bf = bf16(relu(C + b))
// mode 1: f = (resid + relu(C + b))*0.5 ; out_f = f ; out_bf = bf16(f)

__global__ __launch_bounds__(256) void gemm_fused(
    const u16* __restrict__ A, const u16* __restrict__ Wt_hi, const u16* __restrict__ Wt_lo,
    const float* __restrict__ bias, u16* __restrict__ out_bf, float* __restrict__ out_f,
    const float* __restrict__ resid, int mode, int M)
{
    __shared__ u16 sh_h[24 * 64 * 8];    // 24 frag-groups (4 nt x 6 ks) x 64 lanes x 8 shorts
    __shared__ u16 sh_l[24 * 64 * 8];
    int tid = threadIdx.x;
    int nb = blockIdx.y;                 // column third
    const u16* Wh = Wt_hi + (size_t)nb * 64 * H;
    const u16* Wl = Wt_lo + (size_t)nb * 64 * H;

    // stage 64 n-rows x 192 k (hi+lo): 1536 uint4 each, 6 per thread
    #pragma unroll
    for (int i = 0; i < 6; i++) {
        int idx = tid + i * 256;
        int r = idx / 24, s = idx - r * 24;          // r: n-row 0..63, s: k-window 0..23
        int nt = r >> 4, c = r & 15, ks = s >> 2, q = s & 3;
        int p = ((nt * 6 + ks) * 64 + q * 16 + c) * 8;
        *(uint4*)&sh_h[p] = *(const uint4*)(Wh + (size_t)r * H + s * 8);
        *(uint4*)&sh_l[p] = *(const uint4*)(Wl + (size_t)r * H + s * 8);
    }

    int wave = tid >> 6, lane = tid & 63;
    int col = lane & 15, quad = lane >> 4;
    float bv[4];
    #pragma unroll
    for (int nt = 0; nt < 4; nt++) bv[nt] = bias[nb * 64 + nt * 16 + col];
    __syncthreads();

    int NU = (M + 31) >> 5;
    for (int u = blockIdx.x * 4 + wave; u < NU; u += NB_GEMM * 4) {
        int rm = u * 32;
        // A fragments for both 16-row chunks
        short8 a[2][6];
        #pragma unroll
        for (int c = 0; c < 2; c++) {
            int arow = rm + c * 16 + col;
            if (arow >= M) arow = M - 1;
            const u16* Ap = A + (size_t)arow * H + quad * 8;
            #pragma unroll
            for (int ks = 0; ks < 6; ks++) a[c][ks] = *(const short8*)(Ap + ks * 32);
        }
        floatx4 acc[2][4];
        #pragma unroll
        for (int c = 0; c < 2; c++)
            #pragma unroll
            for (int nt = 0; nt < 4; nt++) acc[c][nt] = (floatx4){0.f, 0.f, 0.f, 0.f};

        #pragma unroll
        for (int ks = 0; ks < 6; ks++) {
            #pragma unroll
            for (int nt = 0; nt < 4; nt++) {
                int p = ((nt * 6 + ks) * 64 + lane) * 8;
                short8 bh = *(const short8*)&sh_h[p];
                short8 bl = *(const short8*)&sh_l[p];
                acc[0][nt] = __builtin_amdgcn_mfma_f32_16x16x32_bf16(a[0][ks], bh, acc[0][nt], 0, 0, 0);
                acc[0][nt] = __builtin_amdgcn_mfma_f32_16x16x32_bf16(a[0][ks], bl, acc[0][nt], 0, 0, 0);
                acc[1][nt] = __builtin_amdgcn_mfma_f32_16x16x32_bf16(a[1][ks], bh, acc[1][nt], 0, 0, 0);
                acc[1][nt] = __builtin_amdgcn_mfma_f32_16x16x32_bf16(a[1][ks], bl, acc[1][nt], 0, 0, 0);
            }
        }

        // epilogue: C layout col=lane&15, row=quad*4+r; quarter-wave = 32B u16 runs
        #pragma unroll
        for (int c = 0; c < 2; c++) {
            #pragma unroll
            for (int nt = 0; nt < 4; nt++) {
                int n = nb * 64 + nt * 16 + col;
                #pragma unroll
                for (int r = 0; r < 4; r++) {
                    int row = rm + c * 16 + quad * 4 + r;
                    if (row < M) {
                        float z = fmaxf(acc[c][nt][r] + bv[nt], 0.f);
                        size_t o = (size_t)row * H + n;
                        if (mode == 1) {
                            float f = (resid[o] + z) * 0.5f;
                            out_f[o] = f;
                            out_bf[o] = f2bf(f);
                        } else {
                            out_bf[o] = f2bf(z);
                        }
                    }
                }
            }
        }
    }
}

// ---------------- Output head: coords = (adj@feats) @ W_out + b_out ----------------

__global__ void head_kernel(const u16* __restrict__ A, const float* __restrict__ W,
                            const float* __restrict__ b, float* __restrict__ coords, int M) {
    int row = blockIdx.x * blockDim.x + threadIdx.x;
    if (row >= M) return;
    float a0 = b[0], a1 = b[1], a2 = b[2];
    const u16* Ar = A + (size_t)row * H;
    for (int k = 0; k < H; k++) {
        float x = bf2f(Ar[k]);
        a0 += x * W[k * 3 + 0];
        a1 += x * W[k * 3 + 1];
        a2 += x * W[k * 3 + 2];
    }
    coords[row * 3 + 0] = a0;
    coords[row * 3 + 1] = a1;
    coords[row * 3 + 2] = a2;
}

// ---------------- Launch ----------------

extern "C" void kernel_launch(void* const* d_in, const int* in_sizes, int n_in,
                              void* d_out, int out_size, void* d_ws, size_t ws_size,
                              hipStream_t stream) {
    const float* features = (const float*)d_in[0];
    const int*   edge_src = (const int*)d_in[1];
    const int*   edge_dst = (const int*)d_in[2];
    const float* edge_w   = (const float*)d_in[3];
    const float* Ws       = (const float*)d_in[4];
    const float* bs       = (const float*)d_in[5];
    const float* W_out    = (const float*)d_in[6];
    const float* b_out    = (const float*)d_in[7];

    const int N = in_sizes[0] / H;
    const int E = in_sizes[1];

    float* coords = (float*)d_out;
    float* feats  = coords + (size_t)N * 3;   // fp32 feats output/accumulator

    char* wptr = (char*)d_ws;
    u16* xbuf_bf  = (u16*)wptr;   wptr += (size_t)N * H * sizeof(u16);
    u16* sup      = (u16*)wptr;   wptr += (size_t)N * H * sizeof(u16);
    u16* feats_bf = (u16*)wptr;   wptr += (size_t)N * H * sizeof(u16);
    u16* Wt_hi    = (u16*)wptr;   wptr += (size_t)NLAYER * HH * sizeof(u16);
    u16* Wt_lo    = (u16*)wptr;   wptr += (size_t)NLAYER * HH * sizeof(u16);
    int* counts   = (int*)wptr;   wptr += (size_t)N * sizeof(int);
    int* total    = (int*)wptr;   wptr += 4;                      // contiguous with counts
    int* rbeg     = (int*)wptr;   wptr += (size_t)N * sizeof(int);
    int* rcnt     = (int*)wptr;   wptr += (size_t)N * sizeof(int);
    int* cursor   = (int*)wptr;   wptr += (size_t)N * sizeof(int);
    int2* ce      = (int2*)wptr;  wptr += (size_t)E * sizeof(int2);

    // --- build CSR (dst-indexed, scan-free) ---
    hipMemsetAsync(counts, 0, (size_t)(N + 1) * sizeof(int), stream);  // counts + total
    hist_kernel<<<(E + 255) / 256, 256, 0, stream>>>(edge_dst, counts, E);
    alloc_kernel<<<(N + 255) / 256, 256, 0, stream>>>(counts, rbeg, rcnt, cursor, total, N);
    scatter_kernel<<<(E + 255) / 256, 256, 0, stream>>>(edge_src, edge_dst, edge_w,
                                                        cursor, ce, E);

    // --- weight split/transpose + feature conversion ---
    int wtotal = NLAYER * HH;
    wprep_kernel<<<(wtotal + 255) / 256, 256, 0, stream>>>(Ws, Wt_hi, Wt_lo, wtotal);
    int c4 = N * H / 4;
    conv_kernel<<<(c4 + 255) / 256, 256, 0, stream>>>(features, xbuf_bf, c4);

    dim3 ggrid(NB_GEMM, 3, 1);
    int VC = (N + 23) / 24;

    // L0: agg = adj@f ; x0 = relu(agg W0 + b0)
    spmm_raw<<<VC, 192, 0, stream>>>(xbuf_bf, rbeg, rcnt, ce, sup, N);
    gemm_fused<<<ggrid, 256, 0, stream>>>(sup, Wt_hi + 0 * HH, Wt_lo + 0 * HH, bs + 0 * H,
                                          xbuf_bf, nullptr, nullptr, 0, N);
    // L1: agg = adj@x0 ; feats = (features + relu(agg W1 + b1))/2
    spmm_raw<<<VC, 192, 0, stream>>>(xbuf_bf, rbeg, rcnt, ce, sup, N);
    gemm_fused<<<ggrid, 256, 0, stream>>>(sup, Wt_hi + 1 * HH, Wt_lo + 1 * HH, bs + 1 * H,
                                          feats_bf, feats, features, 1, N);

    // blocks 2-6
    for (int i = 2; i < 12; i += 2) {
        spmm_raw<<<VC, 192, 0, stream>>>(feats_bf, rbeg, rcnt, ce, sup, N);
        gemm_fused<<<ggrid, 256, 0, stream>>>(sup, Wt_hi + (size_t)i * HH, Wt_lo + (size_t)i * HH,
                                              bs + (size_t)i * H, xbuf_bf, nullptr, nullptr, 0, N);
        spmm_raw<<<VC, 192, 0, stream>>>(xbuf_bf, rbeg, rcnt, ce, sup, N);
        gemm_fused<<<ggrid, 256, 0, stream>>>(sup, Wt_hi + (size_t)(i+1) * HH, Wt_lo + (size_t)(i+1) * HH,
                                              bs + (size_t)(i+1) * H, feats_bf, feats, feats, 1, N);
    }

    // gc13
    spmm_raw<<<VC, 192, 0, stream>>>(feats_bf, rbeg, rcnt, ce, sup, N);
    gemm_fused<<<ggrid, 256, 0, stream>>>(sup, Wt_hi + 12 * (size_t)HH, Wt_lo + 12 * (size_t)HH,
                                          bs + 12 * H, feats_bf, feats, feats, 1, N);

    // head: coords = (adj@feats) W_out + b_out
    spmm_raw<<<VC, 192, 0, stream>>>(feats_bf, rbeg, rcnt, ce, sup, N);
    head_kernel<<<(N + 255) / 256, 256, 0, stream>>>(sup, W_out, b_out, coords, N);
}

// Round 9
// 850.202 us; speedup vs baseline: 1.3705x; 1.0988x over previous
//
#include <hip/hip_runtime.h>
#include <hip/hip_bf16.h>

#define H 192
#define HH (192*192)
#define NLAYER 13
#define LSTRIDE (2*HH)         // shorts per layer in fragment-ordered weight buffer

typedef unsigned short u16;
typedef unsigned int u32;

typedef __attribute__((ext_vector_type(8))) short short8;
typedef __attribute__((ext_vector_type(4))) float floatx4;

__device__ __forceinline__ u16 f2bf(float f) {
    u32 u = __float_as_uint(f);
    u32 r = (u + 0x7FFFu + ((u >> 16) & 1u)) >> 16;   // RNE
    return (u16)r;
}
__device__ __forceinline__ float bf2f(u16 h) {
    return __uint_as_float(((u32)h) << 16);
}

// ---------------- CSR construction (scan-free) ----------------

__global__ void hist_kernel(const int* __restrict__ dst, int* __restrict__ counts, int E) {
    int e = blockIdx.x * blockDim.x + threadIdx.x;
    if (e < E) atomicAdd(&counts[dst[e]], 1);
}

__global__ void alloc_kernel(const int* __restrict__ counts, int* __restrict__ rbeg,
                             int* __restrict__ rcnt, int* __restrict__ cursor,
                             int* __restrict__ total, int Nv) {
    int v = blockIdx.x * blockDim.x + threadIdx.x;
    if (v >= Nv) return;
    int c = counts[v];
    int base = atomicAdd(total, c);
    rbeg[v] = base;
    rcnt[v] = c;
    cursor[v] = base;
}

__global__ void scatter_kernel(const int* __restrict__ src, const int* __restrict__ dst,
                               const float* __restrict__ w, int* __restrict__ cursor,
                               int2* __restrict__ ce, int E) {
    int e = blockIdx.x * blockDim.x + threadIdx.x;
    if (e < E) {
        int p = atomicAdd(&cursor[dst[e]], 1);
        int2 pk; pk.x = src[e]; pk.y = __float_as_int(w[e]);
        ce[p] = pk;
    }
}

// ---------------- Weight prep: fragment-ordered, chunk-major ----------------
// Wf[l][group][hl][lane][j], group = ks*12 + nt (k-major => one 64-k chunk of
// hi+lo = 24 groups * 1024 shorts = 48KB contiguous). lane = quad*16 + col
// encodes B[n = nt*16+col][k = ks*32 + quad*8 + j].

__global__ void wprep_kernel(const float* __restrict__ W, u16* __restrict__ Wf, int total) {
    int idx = blockIdx.x * blockDim.x + threadIdx.x;
    if (idx >= total) return;
    int l = idx / HH;
    int rem = idx - l * HH;
    int k = rem / H;
    int n = rem - k * H;
    float v = W[idx];
    u16 hi = f2bf(v);
    u16 lo = f2bf(v - bf2f(hi));
    int ks = k >> 5, quad = (k >> 3) & 3, j = k & 7;
    int nt = n >> 4, col = n & 15;
    int lane = quad * 16 + col;
    size_t base = (size_t)l * LSTRIDE + (size_t)(ks * 12 + nt) * 1024 + lane * 8 + j;
    Wf[base] = hi;
    Wf[base + 512] = lo;
}

// ---------------- features fp32 -> bf16 ----------------

__global__ void conv_kernel(const float* __restrict__ in, u16* __restrict__ out, int total4) {
    int idx = blockIdx.x * blockDim.x + threadIdx.x;
    if (idx >= total4) return;
    float4 v = ((const float4*)in)[idx];
    ushort4 p;
    p.x = f2bf(v.x); p.y = f2bf(v.y); p.z = f2bf(v.z); p.w = f2bf(v.w);
    ((ushort4*)out)[idx] = p;
}

// ---------------- SpMM (pure aggregation): out_bf = adj @ S ----------------

__device__ __forceinline__ void fma8(float acc[8], uint4 q, float w) {
    u32 u[4] = {q.x, q.y, q.z, q.w};
    #pragma unroll
    for (int i = 0; i < 4; i++) {
        float lo = __uint_as_float(u[i] << 16);
        float hi = __uint_as_float(u[i] & 0xFFFF0000u);
        acc[2*i]     += w * lo;
        acc[2*i + 1] += w * hi;
    }
}

__global__ __launch_bounds__(192) void spmm_raw(
    const u16* __restrict__ S, const int* __restrict__ rbeg, const int* __restrict__ rcnt,
    const int2* __restrict__ ce, u16* __restrict__ out, int Nv)
{
    int tid = threadIdx.x;               // 0..191
    int g = tid >> 3;                    // vertex 0..23
    int l = tid & 7;                     // lane within vertex
    int v = blockIdx.x * 24 + g;
    if (v >= Nv) return;
    int beg = rbeg[v], cnt = rcnt[v];
    const int2* cep = ce + beg;
    #pragma unroll
    for (int cg = 0; cg < 3; cg++) {
        int c0 = cg * 64 + l * 8;
        const u16* Sc = S + c0;
        float acc[8] = {};
        int e = 0;
        for (; e + 3 < cnt; e += 4) {
            int2 p0 = cep[e], p1 = cep[e + 1], p2 = cep[e + 2], p3 = cep[e + 3];
            uint4 q0 = *(const uint4*)(Sc + (size_t)p0.x * H);
            uint4 q1 = *(const uint4*)(Sc + (size_t)p1.x * H);
            uint4 q2 = *(const uint4*)(Sc + (size_t)p2.x * H);
            uint4 q3 = *(const uint4*)(Sc + (size_t)p3.x * H);
            fma8(acc, q0, __int_as_float(p0.y));
            fma8(acc, q1, __int_as_float(p1.y));
            fma8(acc, q2, __int_as_float(p2.y));
            fma8(acc, q3, __int_as_float(p3.y));
        }
        for (; e < cnt; e++) {
            int2 p0 = cep[e];
            uint4 q0 = *(const uint4*)(Sc + (size_t)p0.x * H);
            fma8(acc, q0, __int_as_float(p0.y));
        }
        size_t idx = (size_t)v * H + c0;
        ushort4 o0, o1;
        o0.x = f2bf(acc[0]); o0.y = f2bf(acc[1]); o0.z = f2bf(acc[2]); o0.w = f2bf(acc[3]);
        o1.x = f2bf(acc[4]); o1.y = f2bf(acc[5]); o1.z = f2bf(acc[6]); o1.w = f2bf(acc[7]);
        *(ushort4*)&out[idx] = o0;
        *(ushort4*)&out[idx + 4] = o1;
    }
}

// ---------------- MFMA GEMM: wave = 16 rows x full 192 cols, A read once ------
// 3 K-chunks; each chunk's hi+lo weights are a contiguous 48KB span (fragment
// order), staged by linear uint4 copy (coalesced global, conflict-free LDS),
// read back as lane-contiguous ds_read_b128 (conflict-free). No early returns
// (barrier safety); row-guards at stores.
// mode 0: out_bf = bf16(relu(C + b))
// mode 1: f = (resid + relu(C + b))*0.5 ; out_f = f ; out_bf = bf16(f)

__global__ __launch_bounds__(256) void gemm_fused(
    const u16* __restrict__ A, const u16* __restrict__ Wf,
    const float* __restrict__ bias, u16* __restrict__ out_bf, float* __restrict__ out_f,
    const float* __restrict__ resid, int mode, int M)
{
    __shared__ u16 sh[24576];            // 48KB: one K-chunk (24 groups x 1024 shorts)
    int tid = threadIdx.x;
    int wave = tid >> 6, lane = tid & 63;
    int col = lane & 15, quad = lane >> 4;
    int rm = (blockIdx.x * 4 + wave) * 16;

    int arow = rm + col;
    if (arow >= M) arow = M - 1;
    const u16* Ap = A + (size_t)arow * H + quad * 8;
    short8 a[6];
    #pragma unroll
    for (int ks = 0; ks < 6; ks++) a[ks] = *(const short8*)(Ap + ks * 32);

    floatx4 acc[12];
    #pragma unroll
    for (int nt = 0; nt < 12; nt++) acc[nt] = (floatx4){0.f, 0.f, 0.f, 0.f};

    for (int kc = 0; kc < 3; kc++) {
        if (kc) __syncthreads();         // prev chunk reads complete
        const u16* src = Wf + (size_t)kc * 24576;
        #pragma unroll
        for (int i = 0; i < 12; i++) {
            int idx = tid + i * 256;
            *(uint4*)&sh[idx * 8] = *(const uint4*)(src + (size_t)idx * 8);
        }
        __syncthreads();
        #pragma unroll
        for (int ksl = 0; ksl < 2; ksl++) {
            #pragma unroll
            for (int nt = 0; nt < 12; nt++) {
                int p = (ksl * 12 + nt) * 1024 + lane * 8;
                short8 bh = *(const short8*)&sh[p];
                short8 bl = *(const short8*)&sh[p + 512];
                acc[nt] = __builtin_amdgcn_mfma_f32_16x16x32_bf16(a[kc*2+ksl], bh, acc[nt], 0, 0, 0);
                acc[nt] = __builtin_amdgcn_mfma_f32_16x16x32_bf16(a[kc*2+ksl], bl, acc[nt], 0, 0, 0);
            }
        }
    }

    // epilogue: C layout col=lane&15, row=quad*4+r; quarter-wave = 32B u16 runs
    #pragma unroll
    for (int nt = 0; nt < 12; nt++) {
        int n = nt * 16 + col;
        float b = bias[n];
        #pragma unroll
        for (int r = 0; r < 4; r++) {
            int row = rm + quad * 4 + r;
            if (row < M) {
                float z = fmaxf(acc[nt][r] + b, 0.f);
                size_t o = (size_t)row * H + n;
                if (mode == 1) {
                    float f = (resid[o] + z) * 0.5f;
                    out_f[o] = f;
                    out_bf[o] = f2bf(f);
                } else {
                    out_bf[o] = f2bf(z);
                }
            }
        }
    }
}

// ---------------- Output head: coords = (adj@feats) @ W_out + b_out ----------------

__global__ void head_kernel(const u16* __restrict__ A, const float* __restrict__ W,
                            const float* __restrict__ b, float* __restrict__ coords, int M) {
    int row = blockIdx.x * blockDim.x + threadIdx.x;
    if (row >= M) return;
    float a0 = b[0], a1 = b[1], a2 = b[2];
    const u16* Ar = A + (size_t)row * H;
    for (int k = 0; k < H; k++) {
        float x = bf2f(Ar[k]);
        a0 += x * W[k * 3 + 0];
        a1 += x * W[k * 3 + 1];
        a2 += x * W[k * 3 + 2];
    }
    coords[row * 3 + 0] = a0;
    coords[row * 3 + 1] = a1;
    coords[row * 3 + 2] = a2;
}

// ---------------- Launch ----------------

extern "C" void kernel_launch(void* const* d_in, const int* in_sizes, int n_in,
                              void* d_out, int out_size, void* d_ws, size_t ws_size,
                              hipStream_t stream) {
    const float* features = (const float*)d_in[0];
    const int*   edge_src = (const int*)d_in[1];
    const int*   edge_dst = (const int*)d_in[2];
    const float* edge_w   = (const float*)d_in[3];
    const float* Ws       = (const float*)d_in[4];
    const float* bs       = (const float*)d_in[5];
    const float* W_out    = (const float*)d_in[6];
    const float* b_out    = (const float*)d_in[7];

    const int N = in_sizes[0] / H;
    const int E = in_sizes[1];

    float* coords = (float*)d_out;
    float* feats  = coords + (size_t)N * 3;   // fp32 feats output/accumulator

    char* wptr = (char*)d_ws;
    u16* xbuf_bf  = (u16*)wptr;   wptr += (size_t)N * H * sizeof(u16);
    u16* sup      = (u16*)wptr;   wptr += (size_t)N * H * sizeof(u16);
    u16* feats_bf = (u16*)wptr;   wptr += (size_t)N * H * sizeof(u16);
    u16* Wf       = (u16*)wptr;   wptr += (size_t)NLAYER * LSTRIDE * sizeof(u16);
    int* counts   = (int*)wptr;   wptr += (size_t)N * sizeof(int);
    int* total    = (int*)wptr;   wptr += 4;                      // contiguous with counts
    int* rbeg     = (int*)wptr;   wptr += (size_t)N * sizeof(int);
    int* rcnt     = (int*)wptr;   wptr += (size_t)N * sizeof(int);
    int* cursor   = (int*)wptr;   wptr += (size_t)N * sizeof(int);
    int2* ce      = (int2*)wptr;  wptr += (size_t)E * sizeof(int2);

    // --- build CSR (dst-indexed, scan-free) ---
    hipMemsetAsync(counts, 0, (size_t)(N + 1) * sizeof(int), stream);  // counts + total
    hist_kernel<<<(E + 255) / 256, 256, 0, stream>>>(edge_dst, counts, E);
    alloc_kernel<<<(N + 255) / 256, 256, 0, stream>>>(counts, rbeg, rcnt, cursor, total, N);
    scatter_kernel<<<(E + 255) / 256, 256, 0, stream>>>(edge_src, edge_dst, edge_w,
                                                        cursor, ce, E);

    // --- weight split + fragment reorder + feature conversion ---
    int wtotal = NLAYER * HH;
    wprep_kernel<<<(wtotal + 255) / 256, 256, 0, stream>>>(Ws, Wf, wtotal);
    int c4 = N * H / 4;
    conv_kernel<<<(c4 + 255) / 256, 256, 0, stream>>>(features, xbuf_bf, c4);

    int mwaves = (N + 15) / 16;
    int gblocks = (mwaves + 3) / 4;
    int VC = (N + 23) / 24;

    // L0: agg = adj@f ; x0 = relu(agg W0 + b0)
    spmm_raw<<<VC, 192, 0, stream>>>(xbuf_bf, rbeg, rcnt, ce, sup, N);
    gemm_fused<<<gblocks, 256, 0, stream>>>(sup, Wf + 0 * (size_t)LSTRIDE, bs + 0 * H,
                                            xbuf_bf, nullptr, nullptr, 0, N);
    // L1: agg = adj@x0 ; feats = (features + relu(agg W1 + b1))/2
    spmm_raw<<<VC, 192, 0, stream>>>(xbuf_bf, rbeg, rcnt, ce, sup, N);
    gemm_fused<<<gblocks, 256, 0, stream>>>(sup, Wf + 1 * (size_t)LSTRIDE, bs + 1 * H,
                                            feats_bf, feats, features, 1, N);

    // blocks 2-6
    for (int i = 2; i < 12; i += 2) {
        spmm_raw<<<VC, 192, 0, stream>>>(feats_bf, rbeg, rcnt, ce, sup, N);
        gemm_fused<<<gblocks, 256, 0, stream>>>(sup, Wf + (size_t)i * LSTRIDE, bs + (size_t)i * H,
                                                xbuf_bf, nullptr, nullptr, 0, N);
        spmm_raw<<<VC, 192, 0, stream>>>(xbuf_bf, rbeg, rcnt, ce, sup, N);
        gemm_fused<<<gblocks, 256, 0, stream>>>(sup, Wf + (size_t)(i+1) * LSTRIDE, bs + (size_t)(i+1) * H,
                                                feats_bf, feats, feats, 1, N);
    }

    // gc13
    spmm_raw<<<VC, 192, 0, stream>>>(feats_bf, rbeg, rcnt, ce, sup, N);
    gemm_fused<<<gblocks, 256, 0, stream>>>(sup, Wf + 12 * (size_t)LSTRIDE, bs + 12 * H,
                                            feats_bf, feats, feats, 1, N);

    // head: coords = (adj@feats) W_out + b_out
    spmm_raw<<<VC, 192, 0, stream>>>(feats_bf, rbeg, rcnt, ce, sup, N);
    head_kernel<<<(N + 255) / 256, 256, 0, stream>>>(sup, W_out, b_out, coords, N);
}

// Round 10
// 744.924 us; speedup vs baseline: 1.5642x; 1.1413x over previous
//
#include <hip/hip_runtime.h>
#include <hip/hip_bf16.h>

#define H 192
#define HH (192*192)
#define NLAYER 13
#define LSTRIDE (2*HH)         // shorts per layer in fragment-ordered weight buffer

typedef unsigned short u16;
typedef unsigned int u32;

typedef __attribute__((ext_vector_type(8))) short short8;
typedef __attribute__((ext_vector_type(4))) float floatx4;

__device__ __forceinline__ u16 f2bf(float f) {
    u32 u = __float_as_uint(f);
    u32 r = (u + 0x7FFFu + ((u >> 16) & 1u)) >> 16;   // RNE
    return (u16)r;
}
__device__ __forceinline__ float bf2f(u16 h) {
    return __uint_as_float(((u32)h) << 16);
}

// ---------------- CSR construction (scan-free) ----------------

__global__ void hist_kernel(const int* __restrict__ dst, int* __restrict__ counts, int E) {
    int e = blockIdx.x * blockDim.x + threadIdx.x;
    if (e < E) atomicAdd(&counts[dst[e]], 1);
}

__global__ void alloc_kernel(const int* __restrict__ counts, int* __restrict__ rbeg,
                             int* __restrict__ rcnt, int* __restrict__ cursor,
                             int* __restrict__ total, int Nv) {
    int v = blockIdx.x * blockDim.x + threadIdx.x;
    if (v >= Nv) return;
    int c = counts[v];
    int base = atomicAdd(total, c);
    rbeg[v] = base;
    rcnt[v] = c;
    cursor[v] = base;
}

__global__ void scatter_kernel(const int* __restrict__ src, const int* __restrict__ dst,
                               const float* __restrict__ w, int* __restrict__ cursor,
                               int2* __restrict__ ce, int E) {
    int e = blockIdx.x * blockDim.x + threadIdx.x;
    if (e < E) {
        int p = atomicAdd(&cursor[dst[e]], 1);
        int2 pk; pk.x = src[e]; pk.y = __float_as_int(w[e]);
        ce[p] = pk;
    }
}

// ---------------- Weight prep: fragment-ordered, chunk-major ----------------
// Wf[l][group][hl][lane][j], group = ks*12 + nt (k-major => one 64-k chunk of
// hi+lo = 24 groups * 1024 shorts = 48KB contiguous). lane = quad*16 + col
// encodes B[n = nt*16+col][k = ks*32 + quad*8 + j].

__global__ void wprep_kernel(const float* __restrict__ W, u16* __restrict__ Wf, int total) {
    int idx = blockIdx.x * blockDim.x + threadIdx.x;
    if (idx >= total) return;
    int l = idx / HH;
    int rem = idx - l * HH;
    int k = rem / H;
    int n = rem - k * H;
    float v = W[idx];
    u16 hi = f2bf(v);
    u16 lo = f2bf(v - bf2f(hi));
    int ks = k >> 5, quad = (k >> 3) & 3, j = k & 7;
    int nt = n >> 4, col = n & 15;
    int lane = quad * 16 + col;
    size_t base = (size_t)l * LSTRIDE + (size_t)(ks * 12 + nt) * 1024 + lane * 8 + j;
    Wf[base] = hi;
    Wf[base + 512] = lo;
}

// ---------------- features fp32 -> bf16 ----------------

__global__ void conv_kernel(const float* __restrict__ in, u16* __restrict__ out, int total4) {
    int idx = blockIdx.x * blockDim.x + threadIdx.x;
    if (idx >= total4) return;
    float4 v = ((const float4*)in)[idx];
    ushort4 p;
    p.x = f2bf(v.x); p.y = f2bf(v.y); p.z = f2bf(v.z); p.w = f2bf(v.w);
    ((ushort4*)out)[idx] = p;
}

// ---------------- SpMM (pure aggregation): out_bf = adj @ S ----------------
// 24 lanes/vertex, 8 cols/lane: 24 x 16B = one full 384B row per edge in ONE
// vector instruction. 8 vertices per 192-thread block; edges/ce read once.
// Grid = N/8 blocks -> ~9.4k waves (~36/CU) for latency hiding.

__device__ __forceinline__ void fma8(float acc[8], uint4 q, float w) {
    u32 u[4] = {q.x, q.y, q.z, q.w};
    #pragma unroll
    for (int i = 0; i < 4; i++) {
        float lo = __uint_as_float(u[i] << 16);
        float hi = __uint_as_float(u[i] & 0xFFFF0000u);
        acc[2*i]     += w * lo;
        acc[2*i + 1] += w * hi;
    }
}

__global__ __launch_bounds__(192) void spmm_raw(
    const u16* __restrict__ S, const int* __restrict__ rbeg, const int* __restrict__ rcnt,
    const int2* __restrict__ ce, u16* __restrict__ out, int Nv)
{
    int tid = threadIdx.x;               // 0..191
    int g = tid / 24;                    // vertex 0..7
    int l = tid - g * 24;                // lane within vertex, owns cols l*8..l*8+7
    int v = blockIdx.x * 8 + g;
    if (v >= Nv) return;
    int beg = rbeg[v], cnt = rcnt[v];
    const int2* cep = ce + beg;
    const u16* Sc = S + l * 8;
    float acc[8] = {};
    int e = 0;
    for (; e + 3 < cnt; e += 4) {
        int2 p0 = cep[e], p1 = cep[e + 1], p2 = cep[e + 2], p3 = cep[e + 3];
        uint4 q0 = *(const uint4*)(Sc + (size_t)p0.x * H);
        uint4 q1 = *(const uint4*)(Sc + (size_t)p1.x * H);
        uint4 q2 = *(const uint4*)(Sc + (size_t)p2.x * H);
        uint4 q3 = *(const uint4*)(Sc + (size_t)p3.x * H);
        fma8(acc, q0, __int_as_float(p0.y));
        fma8(acc, q1, __int_as_float(p1.y));
        fma8(acc, q2, __int_as_float(p2.y));
        fma8(acc, q3, __int_as_float(p3.y));
    }
    for (; e < cnt; e++) {
        int2 p0 = cep[e];
        uint4 q0 = *(const uint4*)(Sc + (size_t)p0.x * H);
        fma8(acc, q0, __int_as_float(p0.y));
    }
    size_t idx = (size_t)v * H + l * 8;
    ushort4 o0, o1;
    o0.x = f2bf(acc[0]); o0.y = f2bf(acc[1]); o0.z = f2bf(acc[2]); o0.w = f2bf(acc[3]);
    o1.x = f2bf(acc[4]); o1.y = f2bf(acc[5]); o1.z = f2bf(acc[6]); o1.w = f2bf(acc[7]);
    *(ushort4*)&out[idx] = o0;
    *(ushort4*)&out[idx + 4] = o1;
}

// ---------------- MFMA GEMM: wave = 16 rows x full 192 cols, A read once ------
// 3 K-chunks; each chunk's hi+lo weights are a contiguous 48KB span (fragment
// order), staged by linear uint4 copy, read back as lane-contiguous
// ds_read_b128 (conflict-free).
// mode 0: out_bf = bf16(relu(C + b))
// mode 1: f = (bf2f(resid_bf) + relu(C + b))*0.5 ; out_bf = bf16(f)
// mode 2: mode 1 + out_f = f (fp32, final feats)

__global__ __launch_bounds__(256) void gemm_fused(
    const u16* __restrict__ A, const u16* __restrict__ Wf,
    const float* __restrict__ bias, u16* __restrict__ out_bf, float* __restrict__ out_f,
    const u16* __restrict__ resid_bf, int mode, int M)
{
    __shared__ u16 sh[24576];            // 48KB: one K-chunk (24 groups x 1024 shorts)
    int tid = threadIdx.x;
    int wave = tid >> 6, lane = tid & 63;
    int col = lane & 15, quad = lane >> 4;
    int rm = (blockIdx.x * 4 + wave) * 16;

    int arow = rm + col;
    if (arow >= M) arow = M - 1;
    const u16* Ap = A + (size_t)arow * H + quad * 8;
    short8 a[6];
    #pragma unroll
    for (int ks = 0; ks < 6; ks++) a[ks] = *(const short8*)(Ap + ks * 32);

    floatx4 acc[12];
    #pragma unroll
    for (int nt = 0; nt < 12; nt++) acc[nt] = (floatx4){0.f, 0.f, 0.f, 0.f};

    for (int kc = 0; kc < 3; kc++) {
        if (kc) __syncthreads();         // prev chunk reads complete
        const u16* src = Wf + (size_t)kc * 24576;
        #pragma unroll
        for (int i = 0; i < 12; i++) {
            int idx = tid + i * 256;
            *(uint4*)&sh[idx * 8] = *(const uint4*)(src + (size_t)idx * 8);
        }
        __syncthreads();
        #pragma unroll
        for (int ksl = 0; ksl < 2; ksl++) {
            #pragma unroll
            for (int nt = 0; nt < 12; nt++) {
                int p = (ksl * 12 + nt) * 1024 + lane * 8;
                short8 bh = *(const short8*)&sh[p];
                short8 bl = *(const short8*)&sh[p + 512];
                acc[nt] = __builtin_amdgcn_mfma_f32_16x16x32_bf16(a[kc*2+ksl], bh, acc[nt], 0, 0, 0);
                acc[nt] = __builtin_amdgcn_mfma_f32_16x16x32_bf16(a[kc*2+ksl], bl, acc[nt], 0, 0, 0);
            }
        }
    }

    // epilogue: C layout col=lane&15, row=quad*4+r; quarter-wave = 32B u16 runs
    #pragma unroll
    for (int nt = 0; nt < 12; nt++) {
        int n = nt * 16 + col;
        float b = bias[n];
        #pragma unroll
        for (int r = 0; r < 4; r++) {
            int row = rm + quad * 4 + r;
            if (row < M) {
                float z = fmaxf(acc[nt][r] + b, 0.f);
                size_t o = (size_t)row * H + n;
                if (mode >= 1) {
                    float f = (bf2f(resid_bf[o]) + z) * 0.5f;
                    out_bf[o] = f2bf(f);
                    if (mode == 2) out_f[o] = f;
                } else {
                    out_bf[o] = f2bf(z);
                }
            }
        }
    }
}

// ---------------- Output head: coords = (adj@feats) @ W_out + b_out ----------------

__global__ void head_kernel(const u16* __restrict__ A, const float* __restrict__ W,
                            const float* __restrict__ b, float* __restrict__ coords, int M) {
    int row = blockIdx.x * blockDim.x + threadIdx.x;
    if (row >= M) return;
    float a0 = b[0], a1 = b[1], a2 = b[2];
    const u16* Ar = A + (size_t)row * H;
    for (int k = 0; k < H; k++) {
        float x = bf2f(Ar[k]);
        a0 += x * W[k * 3 + 0];
        a1 += x * W[k * 3 + 1];
        a2 += x * W[k * 3 + 2];
    }
    coords[row * 3 + 0] = a0;
    coords[row * 3 + 1] = a1;
    coords[row * 3 + 2] = a2;
}

// ---------------- Launch ----------------

extern "C" void kernel_launch(void* const* d_in, const int* in_sizes, int n_in,
                              void* d_out, int out_size, void* d_ws, size_t ws_size,
                              hipStream_t stream) {
    const float* features = (const float*)d_in[0];
    const int*   edge_src = (const int*)d_in[1];
    const int*   edge_dst = (const int*)d_in[2];
    const float* edge_w   = (const float*)d_in[3];
    const float* Ws       = (const float*)d_in[4];
    const float* bs       = (const float*)d_in[5];
    const float* W_out    = (const float*)d_in[6];
    const float* b_out    = (const float*)d_in[7];

    const int N = in_sizes[0] / H;
    const int E = in_sizes[1];

    float* coords = (float*)d_out;
    float* feats  = coords + (size_t)N * 3;   // fp32 final feats (written at gc13 only)

    char* wptr = (char*)d_ws;
    u16* fbf      = (u16*)wptr;   wptr += (size_t)N * H * sizeof(u16);  // bf16 features (L1 resid)
    u16* xbuf_bf  = (u16*)wptr;   wptr += (size_t)N * H * sizeof(u16);
    u16* sup      = (u16*)wptr;   wptr += (size_t)N * H * sizeof(u16);
    u16* feats_bf = (u16*)wptr;   wptr += (size_t)N * H * sizeof(u16);
    u16* Wf       = (u16*)wptr;   wptr += (size_t)NLAYER * LSTRIDE * sizeof(u16);
    int* counts   = (int*)wptr;   wptr += (size_t)N * sizeof(int);
    int* total    = (int*)wptr;   wptr += 4;                      // contiguous with counts
    int* rbeg     = (int*)wptr;   wptr += (size_t)N * sizeof(int);
    int* rcnt     = (int*)wptr;   wptr += (size_t)N * sizeof(int);
    int* cursor   = (int*)wptr;   wptr += (size_t)N * sizeof(int);
    int2* ce      = (int2*)wptr;  wptr += (size_t)E * sizeof(int2);

    // --- build CSR (dst-indexed, scan-free) ---
    hipMemsetAsync(counts, 0, (size_t)(N + 1) * sizeof(int), stream);  // counts + total
    hist_kernel<<<(E + 255) / 256, 256, 0, stream>>>(edge_dst, counts, E);
    alloc_kernel<<<(N + 255) / 256, 256, 0, stream>>>(counts, rbeg, rcnt, cursor, total, N);
    scatter_kernel<<<(E + 255) / 256, 256, 0, stream>>>(edge_src, edge_dst, edge_w,
                                                        cursor, ce, E);

    // --- weight split + fragment reorder + feature conversion ---
    int wtotal = NLAYER * HH;
    wprep_kernel<<<(wtotal + 255) / 256, 256, 0, stream>>>(Ws, Wf, wtotal);
    int c4 = N * H / 4;
    conv_kernel<<<(c4 + 255) / 256, 256, 0, stream>>>(features, fbf, c4);

    int mwaves = (N + 15) / 16;
    int gblocks = (mwaves + 3) / 4;
    int VC = (N + 7) / 8;

    // L0: agg = adj@f ; x0 = relu(agg W0 + b0)
    spmm_raw<<<VC, 192, 0, stream>>>(fbf, rbeg, rcnt, ce, sup, N);
    gemm_fused<<<gblocks, 256, 0, stream>>>(sup, Wf + 0 * (size_t)LSTRIDE, bs + 0 * H,
                                            xbuf_bf, nullptr, nullptr, 0, N);
    // L1: agg = adj@x0 ; feats = (features + relu(agg W1 + b1))/2
    spmm_raw<<<VC, 192, 0, stream>>>(xbuf_bf, rbeg, rcnt, ce, sup, N);
    gemm_fused<<<gblocks, 256, 0, stream>>>(sup, Wf + 1 * (size_t)LSTRIDE, bs + 1 * H,
                                            feats_bf, nullptr, fbf, 1, N);

    // blocks 2-6
    for (int i = 2; i < 12; i += 2) {
        spmm_raw<<<VC, 192, 0, stream>>>(feats_bf, rbeg, rcnt, ce, sup, N);
        gemm_fused<<<gblocks, 256, 0, stream>>>(sup, Wf + (size_t)i * LSTRIDE, bs + (size_t)i * H,
                                                xbuf_bf, nullptr, nullptr, 0, N);
        spmm_raw<<<VC, 192, 0, stream>>>(xbuf_bf, rbeg, rcnt, ce, sup, N);
        gemm_fused<<<gblocks, 256, 0, stream>>>(sup, Wf + (size_t)(i+1) * LSTRIDE, bs + (size_t)(i+1) * H,
                                                feats_bf, nullptr, feats_bf, 1, N);
    }

    // gc13: writes bf16 feats for head + fp32 feats to d_out
    spmm_raw<<<VC, 192, 0, stream>>>(feats_bf, rbeg, rcnt, ce, sup, N);
    gemm_fused<<<gblocks, 256, 0, stream>>>(sup, Wf + 12 * (size_t)LSTRIDE, bs + 12 * H,
                                            feats_bf, feats, feats_bf, 2, N);

    // head: coords = (adj@feats) W_out + b_out
    spmm_raw<<<VC, 192, 0, stream>>>(feats_bf, rbeg, rcnt, ce, sup, N);
    head_kernel<<<(N + 255) / 256, 256, 0, stream>>>(sup, W_out, b_out, coords, N);
}

// Round 11
// 627.406 us; speedup vs baseline: 1.8571x; 1.1873x over previous
//
#include <hip/hip_runtime.h>
#include <hip/hip_bf16.h>

#define H 192
#define HH (192*192)
#define NLAYER 13
#define LSTRIDE (2*HH)         // shorts per layer in fragment-ordered weight buffer

typedef unsigned short u16;
typedef unsigned int u32;

typedef __attribute__((ext_vector_type(8))) short short8;
typedef __attribute__((ext_vector_type(4))) float floatx4;

__device__ __forceinline__ u16 f2bf(float f) {
    u32 u = __float_as_uint(f);
    u32 r = (u + 0x7FFFu + ((u >> 16) & 1u)) >> 16;   // RNE
    return (u16)r;
}
__device__ __forceinline__ float bf2f(u16 h) {
    return __uint_as_float(((u32)h) << 16);
}

// ---------------- CSR construction (scan-free) ----------------

__global__ void hist_kernel(const int* __restrict__ dst, int* __restrict__ counts, int E) {
    int e = blockIdx.x * blockDim.x + threadIdx.x;
    if (e < E) atomicAdd(&counts[dst[e]], 1);
}

__global__ void alloc_kernel(const int* __restrict__ counts, int* __restrict__ rbeg,
                             int* __restrict__ rcnt, int* __restrict__ cursor,
                             int* __restrict__ total, int Nv) {
    int v = blockIdx.x * blockDim.x + threadIdx.x;
    if (v >= Nv) return;
    int c = counts[v];
    int base = atomicAdd(total, c);
    rbeg[v] = base;
    rcnt[v] = c;
    cursor[v] = base;
}

__global__ void scatter_kernel(const int* __restrict__ src, const int* __restrict__ dst,
                               const float* __restrict__ w, int* __restrict__ cursor,
                               int2* __restrict__ ce, int E) {
    int e = blockIdx.x * blockDim.x + threadIdx.x;
    if (e < E) {
        int p = atomicAdd(&cursor[dst[e]], 1);
        int2 pk; pk.x = src[e]; pk.y = __float_as_int(w[e]);
        ce[p] = pk;
    }
}

// ---------------- Weight prep: fragment-ordered, chunk-major ----------------
// Wf[l][group][hl][lane][j], group = ks*12 + nt; ks in 0..5 (32-k window),
// nt in 0..11. One 32-k sub-chunk (hi+lo of 12 nt groups) = 12288 shorts =
// 24KB contiguous. lane = quad*16 + col encodes B[n=nt*16+col][k=ks*32+quad*8+j].

__global__ void wprep_kernel(const float* __restrict__ W, u16* __restrict__ Wf, int total) {
    int idx = blockIdx.x * blockDim.x + threadIdx.x;
    if (idx >= total) return;
    int l = idx / HH;
    int rem = idx - l * HH;
    int k = rem / H;
    int n = rem - k * H;
    float v = W[idx];
    u16 hi = f2bf(v);
    u16 lo = f2bf(v - bf2f(hi));
    int ks = k >> 5, quad = (k >> 3) & 3, j = k & 7;
    int nt = n >> 4, col = n & 15;
    int lane = quad * 16 + col;
    size_t base = (size_t)l * LSTRIDE + (size_t)(ks * 12 + nt) * 1024 + lane * 8 + j;
    Wf[base] = hi;
    Wf[base + 512] = lo;
}

// ---------------- features fp32 -> bf16 ----------------

__global__ void conv_kernel(const float* __restrict__ in, u16* __restrict__ out, int total4) {
    int idx = blockIdx.x * blockDim.x + threadIdx.x;
    if (idx >= total4) return;
    float4 v = ((const float4*)in)[idx];
    ushort4 p;
    p.x = f2bf(v.x); p.y = f2bf(v.y); p.z = f2bf(v.z); p.w = f2bf(v.w);
    ((ushort4*)out)[idx] = p;
}

// ---------------- common fma helper ----------------

__device__ __forceinline__ void fma8(float* acc, uint4 q, float w) {
    u32 u[4] = {q.x, q.y, q.z, q.w};
    #pragma unroll
    for (int i = 0; i < 4; i++) {
        float lo = __uint_as_float(u[i] << 16);
        float hi = __uint_as_float(u[i] & 0xFFFF0000u);
        acc[2*i]     += w * lo;
        acc[2*i + 1] += w * hi;
    }
}

// ---------------- Fused layer: agg = adj @ S ; out = epilogue(agg @ W + b) ---
// Block = 64 dst rows, 512 threads (8 waves).
// Phase 1: 8 threads/vertex x 64 vertices; thread owns 24 cols (3 x uint4 per
//          edge, 2-edge unroll); result -> LDS A-tile bf16 [64][200].
// Phase 2: 6 weight sub-chunks (24KB, fragment-ordered, linear-copy staged);
//          wave (rw=w&3, cw=w>>2) computes rows rw*16.. x cols cw*96..
//          A-frags via ds_read_b128 from A-tile.
// mode 0: out_bf = bf16(relu(C+b)); mode 1: f=(resid+relu(C+b))*0.5, out_bf;
// mode 2: mode 1 + out_f = f (fp32).

__global__ __launch_bounds__(512) void fused_layer(
    const u16* __restrict__ S, const int* __restrict__ rbeg, const int* __restrict__ rcnt,
    const int2* __restrict__ ce, const u16* __restrict__ Wf, const float* __restrict__ bias,
    u16* __restrict__ out_bf, float* __restrict__ out_f, const u16* __restrict__ resid_bf,
    int mode, int M)
{
    __shared__ u16 shA[64 * 200];        // 25.6 KB A-tile (stride 200 shorts)
    __shared__ u16 shW[12288];           // 24 KB weight sub-chunk
    int tid = threadIdx.x;

    // ---- phase 1: gather ----
    int sub = tid & 7;                   // col group: cols sub*24..+23
    int vg  = tid >> 3;                  // vertex 0..63
    int v = blockIdx.x * 64 + vg;
    int c0 = sub * 24;
    float acc1[24] = {};
    if (v < M) {
        int beg = rbeg[v], cnt = rcnt[v];
        const int2* cep = ce + beg;
        const u16* Sc = S + c0;
        int e = 0;
        for (; e + 1 < cnt; e += 2) {
            int2 p0 = cep[e], p1 = cep[e + 1];
            const u16* r0 = Sc + (size_t)p0.x * H;
            const u16* r1 = Sc + (size_t)p1.x * H;
            uint4 a0 = *(const uint4*)(r0);
            uint4 a1 = *(const uint4*)(r0 + 8);
            uint4 a2 = *(const uint4*)(r0 + 16);
            uint4 b0 = *(const uint4*)(r1);
            uint4 b1 = *(const uint4*)(r1 + 8);
            uint4 b2 = *(const uint4*)(r1 + 16);
            float w0 = __int_as_float(p0.y), w1 = __int_as_float(p1.y);
            fma8(acc1 + 0, a0, w0); fma8(acc1 + 8, a1, w0); fma8(acc1 + 16, a2, w0);
            fma8(acc1 + 0, b0, w1); fma8(acc1 + 8, b1, w1); fma8(acc1 + 16, b2, w1);
        }
        if (e < cnt) {
            int2 p0 = cep[e];
            const u16* r0 = Sc + (size_t)p0.x * H;
            uint4 a0 = *(const uint4*)(r0);
            uint4 a1 = *(const uint4*)(r0 + 8);
            uint4 a2 = *(const uint4*)(r0 + 16);
            float w0 = __int_as_float(p0.y);
            fma8(acc1 + 0, a0, w0); fma8(acc1 + 8, a1, w0); fma8(acc1 + 16, a2, w0);
        }
    }
    {
        u16* dst = &shA[vg * 200 + c0];
        #pragma unroll
        for (int i = 0; i < 3; i++) {
            uint4 p;
            p.x = (u32)f2bf(acc1[8*i+0]) | ((u32)f2bf(acc1[8*i+1]) << 16);
            p.y = (u32)f2bf(acc1[8*i+2]) | ((u32)f2bf(acc1[8*i+3]) << 16);
            p.z = (u32)f2bf(acc1[8*i+4]) | ((u32)f2bf(acc1[8*i+5]) << 16);
            p.w = (u32)f2bf(acc1[8*i+6]) | ((u32)f2bf(acc1[8*i+7]) << 16);
            *(uint4*)(dst + 8 * i) = p;
        }
    }
    __syncthreads();                     // A-tile complete

    // ---- phase 2: MFMA ----
    int wave = tid >> 6, lane = tid & 63;
    int col = lane & 15, quad = lane >> 4;
    int rw = wave & 3, cw = wave >> 2;   // row group / col half

    short8 a[6];
    {
        const u16* Ar = &shA[(rw * 16 + col) * 200 + quad * 8];
        #pragma unroll
        for (int s = 0; s < 6; s++) a[s] = *(const short8*)(Ar + s * 32);
    }
    floatx4 acc[6];
    #pragma unroll
    for (int nt = 0; nt < 6; nt++) acc[nt] = (floatx4){0.f, 0.f, 0.f, 0.f};

    for (int s = 0; s < 6; s++) {
        if (s) __syncthreads();          // prev sub-chunk reads done
        {
            const u16* src = Wf + (size_t)s * 12288;
            #pragma unroll
            for (int i = tid; i < 1536; i += 512)
                *(uint4*)&shW[i * 8] = *(const uint4*)(src + (size_t)i * 8);
        }
        __syncthreads();
        #pragma unroll
        for (int nt = 0; nt < 6; nt++) {
            int p = (cw * 6 + nt) * 1024 + lane * 8;
            short8 bh = *(const short8*)&shW[p];
            short8 bl = *(const short8*)&shW[p + 512];
            acc[nt] = __builtin_amdgcn_mfma_f32_16x16x32_bf16(a[s], bh, acc[nt], 0, 0, 0);
            acc[nt] = __builtin_amdgcn_mfma_f32_16x16x32_bf16(a[s], bl, acc[nt], 0, 0, 0);
        }
    }

    // ---- epilogue: C layout col=lane&15, row=quad*4+r ----
    int rm = blockIdx.x * 64 + rw * 16;
    #pragma unroll
    for (int nt = 0; nt < 6; nt++) {
        int n = (cw * 6 + nt) * 16 + col;
        float b = bias[n];
        #pragma unroll
        for (int r = 0; r < 4; r++) {
            int row = rm + quad * 4 + r;
            if (row < M) {
                float z = fmaxf(acc[nt][r] + b, 0.f);
                size_t o = (size_t)row * H + n;
                if (mode >= 1) {
                    float f = (bf2f(resid_bf[o]) + z) * 0.5f;
                    out_bf[o] = f2bf(f);
                    if (mode == 2) out_f[o] = f;
                } else {
                    out_bf[o] = f2bf(z);
                }
            }
        }
    }
}

// ---------------- head gather: sup = adj @ feats_bf ----------------

__global__ __launch_bounds__(192) void spmm_raw(
    const u16* __restrict__ S, const int* __restrict__ rbeg, const int* __restrict__ rcnt,
    const int2* __restrict__ ce, u16* __restrict__ out, int Nv)
{
    int tid = threadIdx.x;
    int g = tid / 24;
    int l = tid - g * 24;
    int v = blockIdx.x * 8 + g;
    if (v >= Nv) return;
    int beg = rbeg[v], cnt = rcnt[v];
    const int2* cep = ce + beg;
    const u16* Sc = S + l * 8;
    float acc[8] = {};
    int e = 0;
    for (; e + 3 < cnt; e += 4) {
        int2 p0 = cep[e], p1 = cep[e + 1], p2 = cep[e + 2], p3 = cep[e + 3];
        uint4 q0 = *(const uint4*)(Sc + (size_t)p0.x * H);
        uint4 q1 = *(const uint4*)(Sc + (size_t)p1.x * H);
        uint4 q2 = *(const uint4*)(Sc + (size_t)p2.x * H);
        uint4 q3 = *(const uint4*)(Sc + (size_t)p3.x * H);
        fma8(acc, q0, __int_as_float(p0.y));
        fma8(acc, q1, __int_as_float(p1.y));
        fma8(acc, q2, __int_as_float(p2.y));
        fma8(acc, q3, __int_as_float(p3.y));
    }
    for (; e < cnt; e++) {
        int2 p0 = cep[e];
        uint4 q0 = *(const uint4*)(Sc + (size_t)p0.x * H);
        fma8(acc, q0, __int_as_float(p0.y));
    }
    size_t idx = (size_t)v * H + l * 8;
    ushort4 o0, o1;
    o0.x = f2bf(acc[0]); o0.y = f2bf(acc[1]); o0.z = f2bf(acc[2]); o0.w = f2bf(acc[3]);
    o1.x = f2bf(acc[4]); o1.y = f2bf(acc[5]); o1.z = f2bf(acc[6]); o1.w = f2bf(acc[7]);
    *(ushort4*)&out[idx] = o0;
    *(ushort4*)&out[idx + 4] = o1;
}

// ---------------- Output head: coords = sup @ W_out + b_out ----------------

__global__ void head_kernel(const u16* __restrict__ A, const float* __restrict__ W,
                            const float* __restrict__ b, float* __restrict__ coords, int M) {
    int row = blockIdx.x * blockDim.x + threadIdx.x;
    if (row >= M) return;
    float a0 = b[0], a1 = b[1], a2 = b[2];
    const u16* Ar = A + (size_t)row * H;
    for (int k = 0; k < H; k++) {
        float x = bf2f(Ar[k]);
        a0 += x * W[k * 3 + 0];
        a1 += x * W[k * 3 + 1];
        a2 += x * W[k * 3 + 2];
    }
    coords[row * 3 + 0] = a0;
    coords[row * 3 + 1] = a1;
    coords[row * 3 + 2] = a2;
}

// ---------------- Launch ----------------

extern "C" void kernel_launch(void* const* d_in, const int* in_sizes, int n_in,
                              void* d_out, int out_size, void* d_ws, size_t ws_size,
                              hipStream_t stream) {
    const float* features = (const float*)d_in[0];
    const int*   edge_src = (const int*)d_in[1];
    const int*   edge_dst = (const int*)d_in[2];
    const float* edge_w   = (const float*)d_in[3];
    const float* Ws       = (const float*)d_in[4];
    const float* bs       = (const float*)d_in[5];
    const float* W_out    = (const float*)d_in[6];
    const float* b_out    = (const float*)d_in[7];

    const int N = in_sizes[0] / H;
    const int E = in_sizes[1];

    float* coords = (float*)d_out;
    float* feats  = coords + (size_t)N * 3;   // fp32 final feats (written at gc13 only)

    char* wptr = (char*)d_ws;
    u16* fbf      = (u16*)wptr;   wptr += (size_t)N * H * sizeof(u16);
    u16* xb       = (u16*)wptr;   wptr += (size_t)N * H * sizeof(u16);
    u16* sup      = (u16*)wptr;   wptr += (size_t)N * H * sizeof(u16);
    u16* feats_bf = (u16*)wptr;   wptr += (size_t)N * H * sizeof(u16);
    u16* Wf       = (u16*)wptr;   wptr += (size_t)NLAYER * LSTRIDE * sizeof(u16);
    int* counts   = (int*)wptr;   wptr += (size_t)N * sizeof(int);
    int* total    = (int*)wptr;   wptr += 4;
    int* rbeg     = (int*)wptr;   wptr += (size_t)N * sizeof(int);
    int* rcnt     = (int*)wptr;   wptr += (size_t)N * sizeof(int);
    int* cursor   = (int*)wptr;   wptr += (size_t)N * sizeof(int);
    int2* ce      = (int2*)wptr;  wptr += (size_t)E * sizeof(int2);

    // --- build CSR (dst-indexed, scan-free) ---
    hipMemsetAsync(counts, 0, (size_t)(N + 1) * sizeof(int), stream);  // counts + total
    hist_kernel<<<(E + 255) / 256, 256, 0, stream>>>(edge_dst, counts, E);
    alloc_kernel<<<(N + 255) / 256, 256, 0, stream>>>(counts, rbeg, rcnt, cursor, total, N);
    scatter_kernel<<<(E + 255) / 256, 256, 0, stream>>>(edge_src, edge_dst, edge_w,
                                                        cursor, ce, E);

    // --- weight split + fragment reorder + feature conversion ---
    int wtotal = NLAYER * HH;
    wprep_kernel<<<(wtotal + 255) / 256, 256, 0, stream>>>(Ws, Wf, wtotal);
    int c4 = N * H / 4;
    conv_kernel<<<(c4 + 255) / 256, 256, 0, stream>>>(features, fbf, c4);

    int lb = (N + 63) / 64;              // fused-layer blocks
    int VC = (N + 7) / 8;

    // L0: x0 = relu((adj@f) W0 + b0)
    fused_layer<<<lb, 512, 0, stream>>>(fbf, rbeg, rcnt, ce, Wf + 0 * (size_t)LSTRIDE,
                                        bs + 0 * H, xb, nullptr, nullptr, 0, N);
    // L1: feats = (f + relu((adj@x0) W1 + b1))/2
    fused_layer<<<lb, 512, 0, stream>>>(xb, rbeg, rcnt, ce, Wf + 1 * (size_t)LSTRIDE,
                                        bs + 1 * H, feats_bf, nullptr, fbf, 1, N);
    // blocks 2-6
    for (int i = 2; i < 12; i += 2) {
        fused_layer<<<lb, 512, 0, stream>>>(feats_bf, rbeg, rcnt, ce, Wf + (size_t)i * LSTRIDE,
                                            bs + (size_t)i * H, xb, nullptr, nullptr, 0, N);
        fused_layer<<<lb, 512, 0, stream>>>(xb, rbeg, rcnt, ce, Wf + (size_t)(i+1) * LSTRIDE,
                                            bs + (size_t)(i+1) * H, feats_bf, nullptr, feats_bf, 1, N);
    }
    // gc13: also writes fp32 feats to d_out
    fused_layer<<<lb, 512, 0, stream>>>(feats_bf, rbeg, rcnt, ce, Wf + 12 * (size_t)LSTRIDE,
                                        bs + 12 * H, feats_bf, feats, feats_bf, 2, N);

    // head: coords = (adj@feats) W_out + b_out
    spmm_raw<<<VC, 192, 0, stream>>>(feats_bf, rbeg, rcnt, ce, sup, N);
    head_kernel<<<(N + 255) / 256, 256, 0, stream>>>(sup, W_out, b_out, coords, N);
}